// Round 1
// baseline (1229.422 us; speedup 1.0000x reference)
//
#include <hip/hip_runtime.h>
#include <hip/hip_bf16.h>

#define BATCH 2
#define SEQ   2048
#define DMODEL 1024
#define NHEAD 16
#define DEPTH 64

// Allowed diff ranges, derived exactly from the reference mask formula:
// causal AND (|diff|<=32 OR diff==0 OR |log2(diff)-round(log2(diff))|<0.1)
// = union of bands (2^(n-0.1), 2^(n+0.1)) plus local window:
//   [0,34] [60,68] [120,137] [239,274] [478,548] [956,1097] [1911,2047]
// Max entries per row = 35+9+18+36+71+142+137 = 448.
#define NBANDS 7
#define MAXE 448

// ---------------------------------------------------------------------------
// fp32 tiled GEMM: C[M,N] = A[M,K] @ W[K,N] + bias[N]
// BM=64 BN=64 BK=16, 256 threads, 4x4 micro-tile per thread.
// ---------------------------------------------------------------------------
__global__ __launch_bounds__(256) void gemm_bias(
    const float* __restrict__ A, const float* __restrict__ W,
    const float* __restrict__ bias, float* __restrict__ C,
    int M, int N, int K)
{
    __shared__ float As[64][17];   // +1 pad: breaks bank aliasing on column reads
    __shared__ float Ws[16][64];

    const int tid = threadIdx.x;
    const int tx = tid & 15;       // 0..15 -> output col group
    const int ty = tid >> 4;       // 0..15 -> output row group
    const int rowBase = blockIdx.y * 64;
    const int colBase = blockIdx.x * 64;

    float acc[4][4] = {};

    for (int k0 = 0; k0 < K; k0 += 16) {
        // A tile 64x16: each thread one float4
        {
            int r = tid >> 2;            // 0..63
            int c = (tid & 3) * 4;       // 0,4,8,12
            float4 v4 = *(const float4*)(A + (size_t)(rowBase + r) * K + k0 + c);
            As[r][c + 0] = v4.x; As[r][c + 1] = v4.y;
            As[r][c + 2] = v4.z; As[r][c + 3] = v4.w;
        }
        // W tile 16x64: each thread one float4
        {
            int r = tid >> 4;            // 0..15
            int c = (tid & 15) * 4;      // 0..60
            *(float4*)&Ws[r][c] = *(const float4*)(W + (size_t)(k0 + r) * N + colBase + c);
        }
        __syncthreads();
        #pragma unroll
        for (int kk = 0; kk < 16; ++kk) {
            float a0 = As[ty * 4 + 0][kk];
            float a1 = As[ty * 4 + 1][kk];
            float a2 = As[ty * 4 + 2][kk];
            float a3 = As[ty * 4 + 3][kk];
            float4 bv = *(float4*)&Ws[kk][tx * 4];
            acc[0][0] += a0 * bv.x; acc[0][1] += a0 * bv.y; acc[0][2] += a0 * bv.z; acc[0][3] += a0 * bv.w;
            acc[1][0] += a1 * bv.x; acc[1][1] += a1 * bv.y; acc[1][2] += a1 * bv.z; acc[1][3] += a1 * bv.w;
            acc[2][0] += a2 * bv.x; acc[2][1] += a2 * bv.y; acc[2][2] += a2 * bv.z; acc[2][3] += a2 * bv.w;
            acc[3][0] += a3 * bv.x; acc[3][1] += a3 * bv.y; acc[3][2] += a3 * bv.z; acc[3][3] += a3 * bv.w;
        }
        __syncthreads();
    }

    float4 bb = *(const float4*)&bias[colBase + tx * 4];
    #pragma unroll
    for (int ii = 0; ii < 4; ++ii) {
        int row = rowBase + ty * 4 + ii;
        float4 o;
        o.x = acc[ii][0] + bb.x;
        o.y = acc[ii][1] + bb.y;
        o.z = acc[ii][2] + bb.z;
        o.w = acc[ii][3] + bb.w;
        *(float4*)&C[(size_t)row * N + colBase + tx * 4] = o;
    }
}

// ---------------------------------------------------------------------------
// Sparse attention: one wave per query row. Compute <=448 allowed logits,
// softmax over them, write dense attn row (zeros elsewhere), accumulate ctx.
// ---------------------------------------------------------------------------
__global__ __launch_bounds__(256) void attn_kernel(
    const float* __restrict__ qh, const float* __restrict__ kh,
    const float* __restrict__ vh, float* __restrict__ attn,
    float* __restrict__ ctx)
{
    const int BLO[NBANDS] = {0, 60, 120, 239, 478, 956, 1911};
    const int BHI[NBANDS] = {34, 68, 137, 274, 548, 1097, 2047};

    const int wave = threadIdx.x >> 6;
    const int lane = threadIdx.x & 63;
    const int r = blockIdx.x * 4 + wave;          // [0, B*H*S)
    const int b = r >> 15;                        // / (H*S)=32768
    const int h = (r >> 11) & 15;                 // / S % H
    const int i = r & 2047;                       // % S

    __shared__ float p_s[4][MAXE];
    __shared__ int   c_s[4][MAXE];
    __shared__ float q_s[4][64];
    float* p  = p_s[wave];
    int*   cs = c_s[wave];
    float* qv = q_s[wave];

    const size_t hoff = (size_t)h * DEPTH;
    const float* qrow = qh + ((size_t)(b * SEQ + i)) * DMODEL + hoff;
    qv[lane] = qrow[lane];
    __syncthreads();

    // ---- pass 1: logits for allowed cols ----
    float m = -1e30f;
    int cnt = 0;
    for (int band = 0; band < NBANDS; ++band) {
        if (BLO[band] > i) break;
        const int hi = min(BHI[band], i);
        for (int d0 = BLO[band]; d0 <= hi; d0 += 64) {
            const int d = d0 + lane;
            const int n = min(hi - d0 + 1, 64);
            if (d <= hi) {
                const int c = i - d;
                const float4* k4 = (const float4*)(kh + ((size_t)(b * SEQ + c)) * DMODEL + hoff);
                float acc = 0.f;
                #pragma unroll
                for (int t = 0; t < 16; ++t) {
                    float4 kv = k4[t];
                    acc += qv[4 * t + 0] * kv.x + qv[4 * t + 1] * kv.y
                         + qv[4 * t + 2] * kv.z + qv[4 * t + 3] * kv.w;
                }
                float logit = acc * 0.125f;  // / sqrt(64)
                p[cnt + lane] = logit;
                cs[cnt + lane] = c;
                m = fmaxf(m, logit);
            }
            cnt += n;
        }
    }
    __syncthreads();

    // ---- softmax over the cnt allowed entries ----
    #pragma unroll
    for (int off = 32; off; off >>= 1) m = fmaxf(m, __shfl_xor(m, off));
    float sum = 0.f;
    for (int s = lane; s < cnt; s += 64) {
        float e = expf(p[s] - m);
        p[s] = e;
        sum += e;
    }
    #pragma unroll
    for (int off = 32; off; off >>= 1) sum += __shfl_xor(sum, off);
    const float inv = 1.0f / sum;
    for (int s = lane; s < cnt; s += 64) p[s] *= inv;
    __syncthreads();

    // ---- dense attn row write (exact zeros on disallowed) ----
    int pref[NBANDS + 1];
    pref[0] = 0;
    #pragma unroll
    for (int band = 0; band < NBANDS; ++band) {
        int nb = (BLO[band] > i) ? 0 : (min(BHI[band], i) - BLO[band] + 1);
        pref[band + 1] = pref[band] + nb;
    }
    float* arow = attn + (((size_t)(b * NHEAD + h)) * SEQ + i) * SEQ;
    for (int c = lane; c < SEQ; c += 64) {
        const int d = i - c;
        float val = 0.f;
        if (d >= 0) {
            #pragma unroll
            for (int band = 0; band < NBANDS; ++band) {
                if (d >= BLO[band] && d <= BHI[band]) val = p[pref[band] + (d - BLO[band])];
            }
        }
        arow[c] = val;
    }

    // ---- PV: ctx[b,i,h,lane] = sum_s p[s] * vh[b,c_s,h,lane] ----
    float acc = 0.f;
    const float* vbase = vh + (size_t)b * SEQ * DMODEL + hoff + lane;
    #pragma unroll 4
    for (int s = 0; s < cnt; ++s) {
        acc += p[s] * vbase[(size_t)cs[s] * DMODEL];
    }
    ctx[((size_t)(b * SEQ + i)) * DMODEL + hoff + lane] = acc;
}

// ---------------------------------------------------------------------------
extern "C" void kernel_launch(void* const* d_in, const int* in_sizes, int n_in,
                              void* d_out, int out_size, void* d_ws, size_t ws_size,
                              hipStream_t stream) {
    const float* v  = (const float*)d_in[0];
    const float* k  = (const float*)d_in[1];
    const float* q  = (const float*)d_in[2];
    const float* Wq = (const float*)d_in[3];
    const float* bq = (const float*)d_in[4];
    const float* Wk = (const float*)d_in[5];
    const float* bk = (const float*)d_in[6];
    const float* Wv = (const float*)d_in[7];
    const float* bv = (const float*)d_in[8];
    const float* Wo = (const float*)d_in[9];
    const float* bo = (const float*)d_in[10];

    float* ws  = (float*)d_ws;
    float* qh  = ws;                      // 4,194,304 floats each
    float* khp = ws + 4194304;
    float* vhp = ws + 8388608;
    float* ctx = ws + 12582912;           // total 64 MB of workspace

    float* out  = (float*)d_out;          // [B*S, D]
    float* attn = out + 4194304;          // [B, H, S, S]

    const int M = BATCH * SEQ;            // 4096
    dim3 grid(DMODEL / 64, M / 64);       // (16, 64)

    gemm_bias<<<grid, 256, 0, stream>>>(q, Wq, bq, qh,  M, DMODEL, DMODEL);
    gemm_bias<<<grid, 256, 0, stream>>>(k, Wk, bk, khp, M, DMODEL, DMODEL);
    gemm_bias<<<grid, 256, 0, stream>>>(v, Wv, bv, vhp, M, DMODEL, DMODEL);

    attn_kernel<<<(BATCH * NHEAD * SEQ) / 4, 256, 0, stream>>>(qh, khp, vhp, attn, ctx);

    gemm_bias<<<grid, 256, 0, stream>>>(ctx, Wo, bo, out, M, DMODEL, DMODEL);
}

// Round 2
// 770.840 us; speedup vs baseline: 1.5949x; 1.5949x over previous
//
#include <hip/hip_runtime.h>
#include <hip/hip_bf16.h>

#define BATCH 2
#define SEQ   2048
#define DMODEL 1024
#define NHEAD 16
#define DEPTH 64
#define NBANDS 7

// Allowed diffs: causal AND (local<=32 OR |log2(d)-round|<0.1), derived exactly:
//   [0,34] [60,68] [120,137] [239,274] [478,548] [956,1097] [1911,2047]
__device__ __constant__ int cBLO[NBANDS] = {0, 60, 120, 239, 478, 956, 1911};
__device__ __constant__ int cBHI[NBANDS] = {34, 68, 137, 274, 548, 1097, 2047};

typedef __attribute__((ext_vector_type(4))) float f32x4;
typedef __attribute__((ext_vector_type(8))) short bf16x8;
#define MFMA16(a, b, c) __builtin_amdgcn_mfma_f32_16x16x32_bf16(a, b, c, 0, 0, 0)

__device__ __forceinline__ unsigned short f2bf(float x) {
    unsigned int u = __float_as_uint(x);
    u += 0x7fffu + ((u >> 16) & 1u);   // RNE
    return (unsigned short)(u >> 16);
}

// ---------------------------------------------------------------------------
// fp32 tiled GEMM: C[M,N] = A[M,K] @ W[K,N] + bias[N]   (f32 output)
// ---------------------------------------------------------------------------
__global__ __launch_bounds__(256) void gemm_bias(
    const float* __restrict__ A, const float* __restrict__ W,
    const float* __restrict__ bias, float* __restrict__ C,
    int M, int N, int K)
{
    __shared__ float As[64][17];
    __shared__ float Ws[16][64];

    const int tid = threadIdx.x;
    const int tx = tid & 15;
    const int ty = tid >> 4;
    const int rowBase = blockIdx.y * 64;
    const int colBase = blockIdx.x * 64;

    float acc[4][4] = {};

    for (int k0 = 0; k0 < K; k0 += 16) {
        {
            int r = tid >> 2;
            int c = (tid & 3) * 4;
            float4 v4 = *(const float4*)(A + (size_t)(rowBase + r) * K + k0 + c);
            As[r][c + 0] = v4.x; As[r][c + 1] = v4.y;
            As[r][c + 2] = v4.z; As[r][c + 3] = v4.w;
        }
        {
            int r = tid >> 4;
            int c = (tid & 15) * 4;
            *(float4*)&Ws[r][c] = *(const float4*)(W + (size_t)(k0 + r) * N + colBase + c);
        }
        __syncthreads();
        #pragma unroll
        for (int kk = 0; kk < 16; ++kk) {
            float a0 = As[ty * 4 + 0][kk];
            float a1 = As[ty * 4 + 1][kk];
            float a2 = As[ty * 4 + 2][kk];
            float a3 = As[ty * 4 + 3][kk];
            float4 bv = *(float4*)&Ws[kk][tx * 4];
            acc[0][0] += a0 * bv.x; acc[0][1] += a0 * bv.y; acc[0][2] += a0 * bv.z; acc[0][3] += a0 * bv.w;
            acc[1][0] += a1 * bv.x; acc[1][1] += a1 * bv.y; acc[1][2] += a1 * bv.z; acc[1][3] += a1 * bv.w;
            acc[2][0] += a2 * bv.x; acc[2][1] += a2 * bv.y; acc[2][2] += a2 * bv.z; acc[2][3] += a2 * bv.w;
            acc[3][0] += a3 * bv.x; acc[3][1] += a3 * bv.y; acc[3][2] += a3 * bv.z; acc[3][3] += a3 * bv.w;
        }
        __syncthreads();
    }

    float4 bb = *(const float4*)&bias[colBase + tx * 4];
    #pragma unroll
    for (int ii = 0; ii < 4; ++ii) {
        int row = rowBase + ty * 4 + ii;
        float4 o;
        o.x = acc[ii][0] + bb.x;
        o.y = acc[ii][1] + bb.y;
        o.z = acc[ii][2] + bb.z;
        o.w = acc[ii][3] + bb.w;
        *(float4*)&C[(size_t)row * N + colBase + tx * 4] = o;
    }
}

// ---------------------------------------------------------------------------
// same GEMM, bf16 output with post-bias scale (for Q: scale=0.125 exact)
// ---------------------------------------------------------------------------
__global__ __launch_bounds__(256) void gemm_bias_bf16out(
    const float* __restrict__ A, const float* __restrict__ W,
    const float* __restrict__ bias, unsigned short* __restrict__ C,
    int M, int N, int K, float scale)
{
    __shared__ float As[64][17];
    __shared__ float Ws[16][64];

    const int tid = threadIdx.x;
    const int tx = tid & 15;
    const int ty = tid >> 4;
    const int rowBase = blockIdx.y * 64;
    const int colBase = blockIdx.x * 64;

    float acc[4][4] = {};

    for (int k0 = 0; k0 < K; k0 += 16) {
        {
            int r = tid >> 2;
            int c = (tid & 3) * 4;
            float4 v4 = *(const float4*)(A + (size_t)(rowBase + r) * K + k0 + c);
            As[r][c + 0] = v4.x; As[r][c + 1] = v4.y;
            As[r][c + 2] = v4.z; As[r][c + 3] = v4.w;
        }
        {
            int r = tid >> 4;
            int c = (tid & 15) * 4;
            *(float4*)&Ws[r][c] = *(const float4*)(W + (size_t)(k0 + r) * N + colBase + c);
        }
        __syncthreads();
        #pragma unroll
        for (int kk = 0; kk < 16; ++kk) {
            float a0 = As[ty * 4 + 0][kk];
            float a1 = As[ty * 4 + 1][kk];
            float a2 = As[ty * 4 + 2][kk];
            float a3 = As[ty * 4 + 3][kk];
            float4 bv = *(float4*)&Ws[kk][tx * 4];
            acc[0][0] += a0 * bv.x; acc[0][1] += a0 * bv.y; acc[0][2] += a0 * bv.z; acc[0][3] += a0 * bv.w;
            acc[1][0] += a1 * bv.x; acc[1][1] += a1 * bv.y; acc[1][2] += a1 * bv.z; acc[1][3] += a1 * bv.w;
            acc[2][0] += a2 * bv.x; acc[2][1] += a2 * bv.y; acc[2][2] += a2 * bv.z; acc[2][3] += a2 * bv.w;
            acc[3][0] += a3 * bv.x; acc[3][1] += a3 * bv.y; acc[3][2] += a3 * bv.z; acc[3][3] += a3 * bv.w;
        }
        __syncthreads();
    }

    float4 bb = *(const float4*)&bias[colBase + tx * 4];
    #pragma unroll
    for (int ii = 0; ii < 4; ++ii) {
        int row = rowBase + ty * 4 + ii;
        ushort4 o;
        o.x = f2bf((acc[ii][0] + bb.x) * scale);
        o.y = f2bf((acc[ii][1] + bb.y) * scale);
        o.z = f2bf((acc[ii][2] + bb.z) * scale);
        o.w = f2bf((acc[ii][3] + bb.w) * scale);
        *(ushort4*)&C[(size_t)row * N + colBase + tx * 4] = o;
    }
}

// ---------------------------------------------------------------------------
// V transpose+convert: vh f32 [b][c][h*64+d] -> vbT bf16 [b][h][d][c]
// ---------------------------------------------------------------------------
__global__ __launch_bounds__(256) void convert_vT(
    const float* __restrict__ vh, unsigned short* __restrict__ vbT)
{
    const int ct = blockIdx.x, h = blockIdx.y, b = blockIdx.z;
    const int c0 = ct * 64;
    __shared__ float T[64][65];
    const int tid = threadIdx.x;
    {
        int r = tid >> 2, dc = (tid & 3) * 16;
        const float* src = vh + ((size_t)(b * SEQ + c0 + r)) * DMODEL + h * DEPTH + dc;
        #pragma unroll
        for (int j = 0; j < 4; ++j) {
            float4 a = *(const float4*)(src + 4 * j);
            T[r][dc + 4 * j + 0] = a.x;
            T[r][dc + 4 * j + 1] = a.y;
            T[r][dc + 4 * j + 2] = a.z;
            T[r][dc + 4 * j + 3] = a.w;
        }
    }
    __syncthreads();
    {
        int d = tid >> 2, cc = (tid & 3) * 16;
        unsigned int w[8];
        #pragma unroll
        for (int j = 0; j < 8; ++j) {
            unsigned short lo = f2bf(T[cc + 2 * j][d]);
            unsigned short hi = f2bf(T[cc + 2 * j + 1][d]);
            w[j] = (unsigned int)lo | ((unsigned int)hi << 16);
        }
        unsigned short* dst = vbT + ((size_t)((b * NHEAD + h) * DEPTH + d)) * SEQ + c0 + cc;
        uint4 o0 = {w[0], w[1], w[2], w[3]};
        uint4 o1 = {w[4], w[5], w[6], w[7]};
        *(uint4*)dst = o0;
        *(uint4*)(dst + 8) = o1;
    }
}

// ---------------------------------------------------------------------------
// stage a 64x64 bf16 tile into LDS (128B rows) with G4 XOR swizzle
// ---------------------------------------------------------------------------
__device__ __forceinline__ void stage64x64(
    unsigned short* dst, const unsigned short* __restrict__ src,
    int srcStride, int tid)
{
    #pragma unroll
    for (int t = tid; t < 512; t += 256) {
        int row = t >> 3, ch = t & 7;
        uint4 v = *(const uint4*)(src + (size_t)row * srcStride + ch * 8);
        *(uint4*)((char*)dst + row * 128 + ((ch * 16) ^ ((row & 7) << 4))) = v;
    }
}

// ---------------------------------------------------------------------------
// MFMA attention: per (b,h,64-row qtile); 4 waves x 16 q-rows each.
// Pass 1: row sums of exp(logit) over allowed cols. Pass 2: recompute,
// write normalized attn (exact zeros elsewhere), accumulate O = P@V.
// ---------------------------------------------------------------------------
__global__ __launch_bounds__(256) void attn_mfma(
    const unsigned short* __restrict__ qb, const unsigned short* __restrict__ kb,
    const unsigned short* __restrict__ vbT,
    float* __restrict__ attn, float* __restrict__ ctx)
{
    const int tid  = threadIdx.x;
    const int lane = tid & 63;
    const int wave = tid >> 6;
    const int qt = blockIdx.x, h = blockIdx.y, b = blockIdx.z;
    const int i0 = qt * 64;

    __shared__ unsigned short K_lds[64 * 64];
    __shared__ unsigned short V_lds[64 * 64];
    __shared__ unsigned short P_lds[4][16 * 64];
    __shared__ unsigned long long bmask[32];

    // build allowed-diff bitmask (d in [0,2047])
    if (tid < 32) {
        unsigned long long w = 0;
        for (int j = 0; j < 64; ++j) {
            int d = tid * 64 + j;
            bool a = false;
            #pragma unroll
            for (int bb = 0; bb < NBANDS; ++bb)
                a = a || (d >= cBLO[bb] && d <= cBHI[bb]);
            if (a) w |= (1ull << j);
        }
        bmask[tid] = w;
    }

    // active-chunk mask (uniform across block)
    unsigned int amask = 0;
    for (int ch = 0; ch < 32; ++ch) {
        int c0 = ch * 64;
        bool act = false;
        #pragma unroll
        for (int bb = 0; bb < NBANDS; ++bb)
            act = act || ((c0 <= i0 + 63 - cBLO[bb]) && (c0 + 63 >= i0 - cBHI[bb]));
        if (act) amask |= (1u << ch);
    }

    // Q fragments (block-constant): row = lane&15 of this wave's 16 rows
    const int qrow = i0 + wave * 16 + (lane & 15);
    const unsigned short* qptr =
        qb + ((size_t)(b * SEQ + qrow)) * DMODEL + h * DEPTH + (lane >> 4) * 8;
    bf16x8 qa0 = *(const bf16x8*)qptr;
    bf16x8 qa1 = *(const bf16x8*)(qptr + 32);

    const int rgrp = (lane >> 4) << 2;           // this lane's first local row
    const int ibase = i0 + wave * 16 + rgrp;     // global q-row for r=0

    // ---------------- pass 1: row sums ----------------
    float rsum[4] = {0.f, 0.f, 0.f, 0.f};
    for (int ch = 0; ch < 32; ++ch) {
        if (!((amask >> ch) & 1u)) continue;
        const int c0 = ch * 64;
        __syncthreads();
        stage64x64(K_lds, kb + ((size_t)(b * SEQ + c0)) * DMODEL + h * DEPTH, DMODEL, tid);
        __syncthreads();

        f32x4 s[4];
        #pragma unroll
        for (int nt = 0; nt < 4; ++nt) { s[nt].x = 0.f; s[nt].y = 0.f; s[nt].z = 0.f; s[nt].w = 0.f; }
        #pragma unroll
        for (int nt = 0; nt < 4; ++nt) {
            int krow = nt * 16 + (lane & 15);
            const char* kbase = (const char*)K_lds + krow * 128;
            int sw = (krow & 7) << 4;
            bf16x8 b0 = *(const bf16x8*)(kbase + ((((lane >> 4) * 16) + 0) ^ sw));
            bf16x8 b1 = *(const bf16x8*)(kbase + ((((lane >> 4) * 16) + 64) ^ sw));
            s[nt] = MFMA16(qa0, b0, s[nt]);
            s[nt] = MFMA16(qa1, b1, s[nt]);
        }
        #pragma unroll
        for (int nt = 0; nt < 4; ++nt) {
            int c = c0 + nt * 16 + (lane & 15);
            #pragma unroll
            for (int r = 0; r < 4; ++r) {
                int d = ibase + r - c;
                float e = 0.f;
                if (d >= 0 && ((bmask[d >> 6] >> (d & 63)) & 1ull))
                    e = __expf(s[nt][r]);
                rsum[r] += e;
            }
        }
    }
    #pragma unroll
    for (int r = 0; r < 4; ++r) {
        float v = rsum[r];
        v += __shfl_xor(v, 1); v += __shfl_xor(v, 2);
        v += __shfl_xor(v, 4); v += __shfl_xor(v, 8);
        rsum[r] = 1.0f / v;                      // every row has d=0 allowed -> v>0
    }

    // ---------------- pass 2: attn write + PV ----------------
    f32x4 o[4];
    #pragma unroll
    for (int nt = 0; nt < 4; ++nt) { o[nt].x = 0.f; o[nt].y = 0.f; o[nt].z = 0.f; o[nt].w = 0.f; }

    const size_t arowStride = SEQ;
    float* ablock = attn + ((size_t)((b * NHEAD + h) * SEQ)) * SEQ;

    for (int ch = 0; ch < 32; ++ch) {
        const int c0 = ch * 64;
        if (!((amask >> ch) & 1u)) {
            // all-masked chunk: exact zeros, coalesced float4
            float4 z = {0.f, 0.f, 0.f, 0.f};
            #pragma unroll
            for (int rr = 0; rr < 4; ++rr) {
                int i = i0 + wave * 16 + rr * 4 + (lane >> 4);
                *(float4*)(ablock + (size_t)i * arowStride + c0 + (lane & 15) * 4) = z;
            }
            continue;
        }
        __syncthreads();
        stage64x64(K_lds, kb + ((size_t)(b * SEQ + c0)) * DMODEL + h * DEPTH, DMODEL, tid);
        stage64x64(V_lds, vbT + ((size_t)((b * NHEAD + h) * DEPTH)) * SEQ + c0, SEQ, tid);
        __syncthreads();

        f32x4 s[4];
        #pragma unroll
        for (int nt = 0; nt < 4; ++nt) { s[nt].x = 0.f; s[nt].y = 0.f; s[nt].z = 0.f; s[nt].w = 0.f; }
        #pragma unroll
        for (int nt = 0; nt < 4; ++nt) {
            int krow = nt * 16 + (lane & 15);
            const char* kbase = (const char*)K_lds + krow * 128;
            int sw = (krow & 7) << 4;
            bf16x8 b0 = *(const bf16x8*)(kbase + ((((lane >> 4) * 16) + 0) ^ sw));
            bf16x8 b1 = *(const bf16x8*)(kbase + ((((lane >> 4) * 16) + 64) ^ sw));
            s[nt] = MFMA16(qa0, b0, s[nt]);
            s[nt] = MFMA16(qa1, b1, s[nt]);
        }

        char* pwav = (char*)&P_lds[wave][0];
        #pragma unroll
        for (int nt = 0; nt < 4; ++nt) {
            int c = c0 + nt * 16 + (lane & 15);
            #pragma unroll
            for (int r = 0; r < 4; ++r) {
                int row_local = rgrp + r;
                int i = i0 + wave * 16 + row_local;
                int d = i - c;
                float e = 0.f;
                if (d >= 0 && ((bmask[d >> 6] >> (d & 63)) & 1ull))
                    e = __expf(s[nt][r]) * rsum[r];
                ablock[(size_t)i * arowStride + c] = e;
                int colb = (nt * 16 + (lane & 15)) * 2;
                *(unsigned short*)(pwav + row_local * 128 + (colb ^ ((row_local & 7) << 4))) = f2bf(e);
            }
        }
        // P A-fragments (per-wave private LDS; compiler inserts lgkmcnt)
        const char* pbase = (const char*)&P_lds[wave][0] + (lane & 15) * 128;
        int swp = ((lane & 15) & 7) << 4;
        bf16x8 pa0 = *(const bf16x8*)(pbase + ((((lane >> 4) * 16) + 0) ^ swp));
        bf16x8 pa1 = *(const bf16x8*)(pbase + ((((lane >> 4) * 16) + 64) ^ swp));
        #pragma unroll
        for (int nt = 0; nt < 4; ++nt) {
            int vrow = nt * 16 + (lane & 15);
            const char* vbase = (const char*)V_lds + vrow * 128;
            int sw = (vrow & 7) << 4;
            bf16x8 b0 = *(const bf16x8*)(vbase + ((((lane >> 4) * 16) + 0) ^ sw));
            bf16x8 b1 = *(const bf16x8*)(vbase + ((((lane >> 4) * 16) + 64) ^ sw));
            o[nt] = MFMA16(pa0, b0, o[nt]);
            o[nt] = MFMA16(pa1, b1, o[nt]);
        }
    }

    // ---------------- ctx store ----------------
    #pragma unroll
    for (int nt = 0; nt < 4; ++nt) {
        int d = nt * 16 + (lane & 15);
        #pragma unroll
        for (int r = 0; r < 4; ++r) {
            int i = i0 + wave * 16 + rgrp + r;
            ctx[((size_t)(b * SEQ + i)) * DMODEL + h * DEPTH + d] = o[nt][r];
        }
    }
}

// ---------------------------------------------------------------------------
extern "C" void kernel_launch(void* const* d_in, const int* in_sizes, int n_in,
                              void* d_out, int out_size, void* d_ws, size_t ws_size,
                              hipStream_t stream) {
    const float* v  = (const float*)d_in[0];
    const float* k  = (const float*)d_in[1];
    const float* q  = (const float*)d_in[2];
    const float* Wq = (const float*)d_in[3];
    const float* bq = (const float*)d_in[4];
    const float* Wk = (const float*)d_in[5];
    const float* bk = (const float*)d_in[6];
    const float* Wv = (const float*)d_in[7];
    const float* bv = (const float*)d_in[8];
    const float* Wo = (const float*)d_in[9];
    const float* bo = (const float*)d_in[10];

    float* ws = (float*)d_ws;
    float* vh  = ws;                               // 4M f32 = 16 MB
    float* ctx = ws + 4194304;                     // 4M f32 = 16 MB
    unsigned short* qbb = (unsigned short*)(ws + 8388608);   // 4M bf16 = 8 MB
    unsigned short* kbb = qbb + 4194304;                     // 8 MB
    unsigned short* vbT = kbb + 4194304;                     // 8 MB  (56 MB total)

    float* out  = (float*)d_out;                   // [B*S, D]
    float* attn = out + 4194304;                   // [B, H, S, S]

    const int M = BATCH * SEQ;                     // 4096
    dim3 grid(DMODEL / 64, M / 64);                // (16, 64)

    // projections: Q,K straight to bf16 (Q pre-scaled by 1/sqrt(DEPTH)=0.125)
    gemm_bias_bf16out<<<grid, 256, 0, stream>>>(q, Wq, bq, qbb, M, DMODEL, DMODEL, 0.125f);
    gemm_bias_bf16out<<<grid, 256, 0, stream>>>(k, Wk, bk, kbb, M, DMODEL, DMODEL, 1.0f);
    gemm_bias<<<grid, 256, 0, stream>>>(v, Wv, bv, vh, M, DMODEL, DMODEL);

    convert_vT<<<dim3(SEQ / 64, NHEAD, BATCH), 256, 0, stream>>>(vh, vbT);

    attn_mfma<<<dim3(SEQ / 64, NHEAD, BATCH), 256, 0, stream>>>(qbb, kbb, vbT, attn, ctx);

    gemm_bias<<<grid, 256, 0, stream>>>(ctx, Wo, bo, out, M, DMODEL, DMODEL);
}

// Round 3
// 607.160 us; speedup vs baseline: 2.0249x; 1.2696x over previous
//
#include <hip/hip_runtime.h>
#include <hip/hip_bf16.h>

#define BATCH 2
#define SEQ   2048
#define DMODEL 1024
#define NHEAD 16
#define DEPTH 64
#define NBANDS 7

// Allowed diffs: causal AND (local<=32 OR |log2(d)-round|<0.1), derived exactly:
//   [0,34] [60,68] [120,137] [239,274] [478,548] [956,1097] [1911,2047]
__device__ __constant__ int cBLO[NBANDS] = {0, 60, 120, 239, 478, 956, 1911};
__device__ __constant__ int cBHI[NBANDS] = {34, 68, 137, 274, 548, 1097, 2047};

typedef __attribute__((ext_vector_type(4))) float f32x4;
typedef __attribute__((ext_vector_type(8))) short bf16x8;
#define MFMA16(a, b, c) __builtin_amdgcn_mfma_f32_16x16x32_bf16(a, b, c, 0, 0, 0)

__device__ __forceinline__ unsigned short f2bf(float x) {
    unsigned int u = __float_as_uint(x);
    u += 0x7fffu + ((u >> 16) & 1u);   // RNE
    return (unsigned short)(u >> 16);
}
__device__ __forceinline__ float bf2f(unsigned short h) {
    return __uint_as_float((unsigned int)h << 16);
}

// ---------------------------------------------------------------------------
// split convert: x f32 [4096][1024] -> out bf16 [4096][3072] = [hi | lo | hi]
// ---------------------------------------------------------------------------
__global__ __launch_bounds__(256) void cvt_split(
    const float* __restrict__ x, unsigned short* __restrict__ out)
{
    size_t t = (size_t)blockIdx.x * 256 + threadIdx.x;   // < 524288
    size_t f = t * 8;
    int m = (int)(f >> 10), kk = (int)(f & 1023);
    float4 v0 = *(const float4*)(x + f);
    float4 v1 = *(const float4*)(x + f + 4);
    float v[8] = {v0.x, v0.y, v0.z, v0.w, v1.x, v1.y, v1.z, v1.w};
    unsigned short hi[8], lo[8];
    #pragma unroll
    for (int j = 0; j < 8; ++j) {
        hi[j] = f2bf(v[j]);
        lo[j] = f2bf(v[j] - bf2f(hi[j]));
    }
    unsigned short* row = out + (size_t)m * 3072 + kk;
    *(uint4*)row          = *(uint4*)hi;
    *(uint4*)(row + 2048) = *(uint4*)hi;
    *(uint4*)(row + 1024) = *(uint4*)lo;
}

// plain convert: f32 [4096][1024] -> bf16 [4096][1024]
__global__ __launch_bounds__(256) void cvt_plain(
    const float* __restrict__ x, unsigned short* __restrict__ out)
{
    size_t t = (size_t)blockIdx.x * 256 + threadIdx.x;
    size_t f = t * 8;
    float4 v0 = *(const float4*)(x + f);
    float4 v1 = *(const float4*)(x + f + 4);
    float v[8] = {v0.x, v0.y, v0.z, v0.w, v1.x, v1.y, v1.z, v1.w};
    unsigned short hi[8];
    #pragma unroll
    for (int j = 0; j < 8; ++j) hi[j] = f2bf(v[j]);
    *(uint4*)(out + f) = *(uint4*)hi;
}

// ---------------------------------------------------------------------------
// weight transpose+convert: W f32 [1024][1024] -> WT bf16 [1024][Kout]
// SPLIT: WT[n] = [Whi(k) | Whi(k) | Wlo(k)] (Kout=3072); else hi only (1024).
// ---------------------------------------------------------------------------
template<int SPLIT>
__global__ __launch_bounds__(256) void cvt_wT(
    const float* __restrict__ W, unsigned short* __restrict__ WT)
{
    const int k0 = blockIdx.x * 64, n0 = blockIdx.y * 64;
    __shared__ float T[64][65];
    const int t = threadIdx.x;
    const int r = t >> 2, cc = (t & 3) * 16;
    {
        const float* src = W + (size_t)(k0 + r) * 1024 + n0 + cc;
        #pragma unroll
        for (int j = 0; j < 4; ++j) {
            float4 a = *(const float4*)(src + 4 * j);
            T[r][cc + 4 * j + 0] = a.x; T[r][cc + 4 * j + 1] = a.y;
            T[r][cc + 4 * j + 2] = a.z; T[r][cc + 4 * j + 3] = a.w;
        }
    }
    __syncthreads();
    const int d = t >> 2;                     // local n
    unsigned short hi[16], lo[16];
    #pragma unroll
    for (int j = 0; j < 16; ++j) {
        float v = T[cc + j][d];
        hi[j] = f2bf(v);
        if (SPLIT) lo[j] = f2bf(v - bf2f(hi[j]));
    }
    const int Kout = SPLIT ? 3072 : 1024;
    unsigned short* dst = WT + (size_t)(n0 + d) * Kout + k0 + cc;
    *(uint4*)dst       = *(uint4*)hi;
    *(uint4*)(dst + 8) = *(uint4*)(hi + 8);
    if (SPLIT) {
        *(uint4*)(dst + 1024)     = *(uint4*)hi;
        *(uint4*)(dst + 1024 + 8) = *(uint4*)(hi + 8);
        *(uint4*)(dst + 2048)     = *(uint4*)lo;
        *(uint4*)(dst + 2048 + 8) = *(uint4*)(lo + 8);
    }
}

// ---------------------------------------------------------------------------
// bf16 MFMA GEMM: C[M,1024] = A[M,Kc] @ BT[1024,Kc]^T + bias, optional scale.
// 128x128 tile, BK=64, 256 threads = 4 waves (2x2), reg-staged XOR-swz LDS.
// ---------------------------------------------------------------------------
template<int OUT_BF16>
__global__ __launch_bounds__(256) void gemm_mfma(
    const unsigned short* __restrict__ A, const unsigned short* __restrict__ BT,
    const float* __restrict__ bias, void* __restrict__ Cout,
    int Kc, float scale)
{
    __shared__ unsigned short Atile[128 * 64];
    __shared__ unsigned short Btile[128 * 64];
    const int tid  = threadIdx.x;
    const int lane = tid & 63;
    const int wave = tid >> 6;
    const int wm = (wave >> 1) * 64;
    const int wn = (wave & 1) * 64;
    const int rowBase = blockIdx.y * 128;
    const int colBase = blockIdx.x * 128;

    f32x4 acc[4][4];
    #pragma unroll
    for (int mt = 0; mt < 4; ++mt)
        #pragma unroll
        for (int nt = 0; nt < 4; ++nt) {
            acc[mt][nt].x = 0.f; acc[mt][nt].y = 0.f;
            acc[mt][nt].z = 0.f; acc[mt][nt].w = 0.f;
        }

    const int srow = tid >> 3;            // 0..31 (+32 per i)
    const int sch  = tid & 7;
    uint4 ar[4], br[4];

    #define ISSUE(k0)                                                          \
        _Pragma("unroll")                                                      \
        for (int i = 0; i < 4; ++i) {                                          \
            int row = srow + i * 32;                                           \
            ar[i] = *(const uint4*)(A  + (size_t)(rowBase + row) * Kc + (k0) + sch * 8); \
            br[i] = *(const uint4*)(BT + (size_t)(colBase + row) * Kc + (k0) + sch * 8); \
        }

    ISSUE(0)
    const int nk = Kc >> 6;
    for (int t = 0; t < nk; ++t) {
        __syncthreads();
        #pragma unroll
        for (int i = 0; i < 4; ++i) {
            int row = srow + i * 32;
            int off = row * 128 + ((sch * 16) ^ ((row & 7) << 4));
            *(uint4*)((char*)Atile + off) = ar[i];
            *(uint4*)((char*)Btile + off) = br[i];
        }
        __syncthreads();
        if (t + 1 < nk) { int k0n = (t + 1) << 6; ISSUE(k0n) }

        bf16x8 a0[4], a1[4];
        const int g = (lane >> 4) * 16;
        #pragma unroll
        for (int mt = 0; mt < 4; ++mt) {
            int arow = wm + mt * 16 + (lane & 15);
            const char* base = (const char*)Atile + arow * 128;
            int sw = (arow & 7) << 4;
            a0[mt] = *(const bf16x8*)(base + (g ^ sw));
            a1[mt] = *(const bf16x8*)(base + ((g + 64) ^ sw));
        }
        #pragma unroll
        for (int nt = 0; nt < 4; ++nt) {
            int brow = wn + nt * 16 + (lane & 15);
            const char* base = (const char*)Btile + brow * 128;
            int sw = (brow & 7) << 4;
            bf16x8 b0 = *(const bf16x8*)(base + (g ^ sw));
            bf16x8 b1 = *(const bf16x8*)(base + ((g + 64) ^ sw));
            #pragma unroll
            for (int mt = 0; mt < 4; ++mt) {
                acc[mt][nt] = MFMA16(a0[mt], b0, acc[mt][nt]);
                acc[mt][nt] = MFMA16(a1[mt], b1, acc[mt][nt]);
            }
        }
    }
    #undef ISSUE

    #pragma unroll
    for (int nt = 0; nt < 4; ++nt) {
        int col = colBase + wn + nt * 16 + (lane & 15);
        float bv = bias[col];
        #pragma unroll
        for (int mt = 0; mt < 4; ++mt) {
            #pragma unroll
            for (int r = 0; r < 4; ++r) {
                int row = rowBase + wm + mt * 16 + (lane >> 4) * 4 + r;
                float val = (acc[mt][nt][r] + bv) * scale;
                if (OUT_BF16)
                    ((unsigned short*)Cout)[(size_t)row * 1024 + col] = f2bf(val);
                else
                    ((float*)Cout)[(size_t)row * 1024 + col] = val;
            }
        }
    }
}

// ---------------------------------------------------------------------------
// V transpose+convert: vh f32 [b][c][h*64+d] -> vbT bf16 [b][h][d][c]
// ---------------------------------------------------------------------------
__global__ __launch_bounds__(256) void convert_vT(
    const float* __restrict__ vh, unsigned short* __restrict__ vbT)
{
    const int ct = blockIdx.x, h = blockIdx.y, b = blockIdx.z;
    const int c0 = ct * 64;
    __shared__ float T[64][65];
    const int tid = threadIdx.x;
    {
        int r = tid >> 2, dc = (tid & 3) * 16;
        const float* src = vh + ((size_t)(b * SEQ + c0 + r)) * DMODEL + h * DEPTH + dc;
        #pragma unroll
        for (int j = 0; j < 4; ++j) {
            float4 a = *(const float4*)(src + 4 * j);
            T[r][dc + 4 * j + 0] = a.x;
            T[r][dc + 4 * j + 1] = a.y;
            T[r][dc + 4 * j + 2] = a.z;
            T[r][dc + 4 * j + 3] = a.w;
        }
    }
    __syncthreads();
    {
        int d = tid >> 2, cc = (tid & 3) * 16;
        unsigned int w[8];
        #pragma unroll
        for (int j = 0; j < 8; ++j) {
            unsigned short lo = f2bf(T[cc + 2 * j][d]);
            unsigned short hi = f2bf(T[cc + 2 * j + 1][d]);
            w[j] = (unsigned int)lo | ((unsigned int)hi << 16);
        }
        unsigned short* dst = vbT + ((size_t)((b * NHEAD + h) * DEPTH + d)) * SEQ + c0 + cc;
        uint4 o0 = {w[0], w[1], w[2], w[3]};
        uint4 o1 = {w[4], w[5], w[6], w[7]};
        *(uint4*)dst = o0;
        *(uint4*)(dst + 8) = o1;
    }
}

// ---------------------------------------------------------------------------
// stage a 64x64 bf16 tile into LDS (128B rows) with G4 XOR swizzle
// ---------------------------------------------------------------------------
__device__ __forceinline__ void stage64x64(
    unsigned short* dst, const unsigned short* __restrict__ src,
    int srcStride, int tid)
{
    #pragma unroll
    for (int t = tid; t < 512; t += 256) {
        int row = t >> 3, ch = t & 7;
        uint4 v = *(const uint4*)(src + (size_t)row * srcStride + ch * 8);
        *(uint4*)((char*)dst + row * 128 + ((ch * 16) ^ ((row & 7) << 4))) = v;
    }
}

// ---------------------------------------------------------------------------
// MFMA attention: per (b,h,64-row qtile); 4 waves x 16 q-rows each.
// Pass 1: row sums of exp(logit) over allowed cols. Pass 2: recompute,
// write normalized attn (exact zeros elsewhere), accumulate O = P@V.
// ctx written as bf16 (feeds bf16 out-projection GEMM).
// ---------------------------------------------------------------------------
__global__ __launch_bounds__(256) void attn_mfma(
    const unsigned short* __restrict__ qb, const unsigned short* __restrict__ kb,
    const unsigned short* __restrict__ vbT,
    float* __restrict__ attn, unsigned short* __restrict__ ctxb)
{
    const int tid  = threadIdx.x;
    const int lane = tid & 63;
    const int wave = tid >> 6;
    const int qt = blockIdx.x, h = blockIdx.y, b = blockIdx.z;
    const int i0 = qt * 64;

    __shared__ unsigned short K_lds[64 * 64];
    __shared__ unsigned short V_lds[64 * 64];
    __shared__ unsigned short P_lds[4][16 * 64];
    __shared__ unsigned long long bmask[32];

    if (tid < 32) {
        unsigned long long w = 0;
        for (int j = 0; j < 64; ++j) {
            int d = tid * 64 + j;
            bool a = false;
            #pragma unroll
            for (int bb = 0; bb < NBANDS; ++bb)
                a = a || (d >= cBLO[bb] && d <= cBHI[bb]);
            if (a) w |= (1ull << j);
        }
        bmask[tid] = w;
    }

    unsigned int amask = 0;
    for (int ch = 0; ch < 32; ++ch) {
        int c0 = ch * 64;
        bool act = false;
        #pragma unroll
        for (int bb = 0; bb < NBANDS; ++bb)
            act = act || ((c0 <= i0 + 63 - cBLO[bb]) && (c0 + 63 >= i0 - cBHI[bb]));
        if (act) amask |= (1u << ch);
    }

    const int qrow = i0 + wave * 16 + (lane & 15);
    const unsigned short* qptr =
        qb + ((size_t)(b * SEQ + qrow)) * DMODEL + h * DEPTH + (lane >> 4) * 8;
    bf16x8 qa0 = *(const bf16x8*)qptr;
    bf16x8 qa1 = *(const bf16x8*)(qptr + 32);

    const int rgrp = (lane >> 4) << 2;
    const int ibase = i0 + wave * 16 + rgrp;

    // ---------------- pass 1: row sums ----------------
    float rsum[4] = {0.f, 0.f, 0.f, 0.f};
    for (int ch = 0; ch < 32; ++ch) {
        if (!((amask >> ch) & 1u)) continue;
        const int c0 = ch * 64;
        __syncthreads();
        stage64x64(K_lds, kb + ((size_t)(b * SEQ + c0)) * DMODEL + h * DEPTH, DMODEL, tid);
        __syncthreads();

        f32x4 s[4];
        #pragma unroll
        for (int nt = 0; nt < 4; ++nt) { s[nt].x = 0.f; s[nt].y = 0.f; s[nt].z = 0.f; s[nt].w = 0.f; }
        #pragma unroll
        for (int nt = 0; nt < 4; ++nt) {
            int krow = nt * 16 + (lane & 15);
            const char* kbase = (const char*)K_lds + krow * 128;
            int sw = (krow & 7) << 4;
            bf16x8 b0 = *(const bf16x8*)(kbase + ((((lane >> 4) * 16) + 0) ^ sw));
            bf16x8 b1 = *(const bf16x8*)(kbase + ((((lane >> 4) * 16) + 64) ^ sw));
            s[nt] = MFMA16(qa0, b0, s[nt]);
            s[nt] = MFMA16(qa1, b1, s[nt]);
        }
        #pragma unroll
        for (int nt = 0; nt < 4; ++nt) {
            int c = c0 + nt * 16 + (lane & 15);
            #pragma unroll
            for (int r = 0; r < 4; ++r) {
                int d = ibase + r - c;
                float e = 0.f;
                if (d >= 0 && ((bmask[d >> 6] >> (d & 63)) & 1ull))
                    e = __expf(s[nt][r]);
                rsum[r] += e;
            }
        }
    }
    #pragma unroll
    for (int r = 0; r < 4; ++r) {
        float v = rsum[r];
        v += __shfl_xor(v, 1); v += __shfl_xor(v, 2);
        v += __shfl_xor(v, 4); v += __shfl_xor(v, 8);
        rsum[r] = 1.0f / v;
    }

    // ---------------- pass 2: attn write + PV ----------------
    f32x4 o[4];
    #pragma unroll
    for (int nt = 0; nt < 4; ++nt) { o[nt].x = 0.f; o[nt].y = 0.f; o[nt].z = 0.f; o[nt].w = 0.f; }

    float* ablock = attn + ((size_t)((b * NHEAD + h) * SEQ)) * SEQ;

    for (int ch = 0; ch < 32; ++ch) {
        const int c0 = ch * 64;
        if (!((amask >> ch) & 1u)) {
            float4 z = {0.f, 0.f, 0.f, 0.f};
            #pragma unroll
            for (int rr = 0; rr < 4; ++rr) {
                int i = i0 + wave * 16 + rr * 4 + (lane >> 4);
                *(float4*)(ablock + (size_t)i * SEQ + c0 + (lane & 15) * 4) = z;
            }
            continue;
        }
        __syncthreads();
        stage64x64(K_lds, kb + ((size_t)(b * SEQ + c0)) * DMODEL + h * DEPTH, DMODEL, tid);
        stage64x64(V_lds, vbT + ((size_t)((b * NHEAD + h) * DEPTH)) * SEQ + c0, SEQ, tid);
        __syncthreads();

        f32x4 s[4];
        #pragma unroll
        for (int nt = 0; nt < 4; ++nt) { s[nt].x = 0.f; s[nt].y = 0.f; s[nt].z = 0.f; s[nt].w = 0.f; }
        #pragma unroll
        for (int nt = 0; nt < 4; ++nt) {
            int krow = nt * 16 + (lane & 15);
            const char* kbase = (const char*)K_lds + krow * 128;
            int sw = (krow & 7) << 4;
            bf16x8 b0 = *(const bf16x8*)(kbase + ((((lane >> 4) * 16) + 0) ^ sw));
            bf16x8 b1 = *(const bf16x8*)(kbase + ((((lane >> 4) * 16) + 64) ^ sw));
            s[nt] = MFMA16(qa0, b0, s[nt]);
            s[nt] = MFMA16(qa1, b1, s[nt]);
        }

        char* pwav = (char*)&P_lds[wave][0];
        #pragma unroll
        for (int nt = 0; nt < 4; ++nt) {
            int c = c0 + nt * 16 + (lane & 15);
            #pragma unroll
            for (int r = 0; r < 4; ++r) {
                int row_local = rgrp + r;
                int i = i0 + wave * 16 + row_local;
                int d = i - c;
                float e = 0.f;
                if (d >= 0 && ((bmask[d >> 6] >> (d & 63)) & 1ull))
                    e = __expf(s[nt][r]) * rsum[r];
                ablock[(size_t)i * SEQ + c] = e;
                int colb = (nt * 16 + (lane & 15)) * 2;
                *(unsigned short*)(pwav + row_local * 128 + (colb ^ ((row_local & 7) << 4))) = f2bf(e);
            }
        }
        const char* pbase = (const char*)&P_lds[wave][0] + (lane & 15) * 128;
        int swp = ((lane & 15) & 7) << 4;
        bf16x8 pa0 = *(const bf16x8*)(pbase + ((((lane >> 4) * 16) + 0) ^ swp));
        bf16x8 pa1 = *(const bf16x8*)(pbase + ((((lane >> 4) * 16) + 64) ^ swp));
        #pragma unroll
        for (int nt = 0; nt < 4; ++nt) {
            int vrow = nt * 16 + (lane & 15);
            const char* vbase = (const char*)V_lds + vrow * 128;
            int sw = (vrow & 7) << 4;
            bf16x8 b0 = *(const bf16x8*)(vbase + ((((lane >> 4) * 16) + 0) ^ sw));
            bf16x8 b1 = *(const bf16x8*)(vbase + ((((lane >> 4) * 16) + 64) ^ sw));
            o[nt] = MFMA16(pa0, b0, o[nt]);
            o[nt] = MFMA16(pa1, b1, o[nt]);
        }
    }

    // ---------------- ctx store (bf16) ----------------
    #pragma unroll
    for (int nt = 0; nt < 4; ++nt) {
        int d = nt * 16 + (lane & 15);
        #pragma unroll
        for (int r = 0; r < 4; ++r) {
            int i = i0 + wave * 16 + rgrp + r;
            ctxb[((size_t)(b * SEQ + i)) * DMODEL + h * DEPTH + d] = f2bf(o[nt][r]);
        }
    }
}

// ---------------------------------------------------------------------------
extern "C" void kernel_launch(void* const* d_in, const int* in_sizes, int n_in,
                              void* d_out, int out_size, void* d_ws, size_t ws_size,
                              hipStream_t stream) {
    const float* v  = (const float*)d_in[0];
    const float* k  = (const float*)d_in[1];
    const float* q  = (const float*)d_in[2];
    const float* Wq = (const float*)d_in[3];
    const float* bq = (const float*)d_in[4];
    const float* Wk = (const float*)d_in[5];
    const float* bk = (const float*)d_in[6];
    const float* Wv = (const float*)d_in[7];
    const float* bv = (const float*)d_in[8];
    const float* Wo = (const float*)d_in[9];
    const float* bo = (const float*)d_in[10];

    float* out  = (float*)d_out;                   // [B*S, D]
    float* attn = out + 4194304;                   // [B, H, S, S]  (512 MB)

    // --- d_ws layout (60 MB) ---
    float* ws = (float*)d_ws;
    float* vh = ws;                                          // 16 MB f32
    unsigned short* qbb  = (unsigned short*)(ws + 4194304);  // 8 MB bf16
    unsigned short* kbb  = qbb  + 4194304;                   // 8 MB
    unsigned short* vbT  = kbb  + 4194304;                   // 8 MB
    unsigned short* ctxb = vbT  + 4194304;                   // 8 MB
    unsigned short* vb16 = ctxb + 4194304;                   // 8 MB
    unsigned short* WvT  = vb16 + 4194304;                   // 2 MB
    unsigned short* WoT  = WvT  + 1048576;                   // 2 MB

    // --- scratch inside attn region (overwritten by attn_mfma later) ---
    unsigned short* qs    = (unsigned short*)attn;           // [4096][3072] 24 MB
    unsigned short* ks    = qs + 12582912;                   // 24 MB
    unsigned short* WqTs  = ks + 12582912;                   // [1024][3072] 6 MB
    unsigned short* WkTs  = WqTs + 3145728;                  // 6 MB

    // converts
    cvt_split<<<2048, 256, 0, stream>>>(q, qs);
    cvt_split<<<2048, 256, 0, stream>>>(k, ks);
    cvt_plain<<<2048, 256, 0, stream>>>(v, vb16);
    cvt_wT<1><<<dim3(16, 16), 256, 0, stream>>>(Wq, WqTs);
    cvt_wT<1><<<dim3(16, 16), 256, 0, stream>>>(Wk, WkTs);
    cvt_wT<0><<<dim3(16, 16), 256, 0, stream>>>(Wv, WvT);
    cvt_wT<0><<<dim3(16, 16), 256, 0, stream>>>(Wo, WoT);

    // projections (MFMA): Q,K compensated split-bf16 (K=3072), V plain (K=1024)
    dim3 ggrid(8, 32);   // (N/128, M/128)
    gemm_mfma<1><<<ggrid, 256, 0, stream>>>(qs, WqTs, bq, qbb, 3072, 0.125f);
    gemm_mfma<1><<<ggrid, 256, 0, stream>>>(ks, WkTs, bk, kbb, 3072, 1.0f);
    gemm_mfma<0><<<ggrid, 256, 0, stream>>>(vb16, WvT, bv, vh, 1024, 1.0f);

    convert_vT<<<dim3(SEQ / 64, NHEAD, BATCH), 256, 0, stream>>>(vh, vbT);

    attn_mfma<<<dim3(SEQ / 64, NHEAD, BATCH), 256, 0, stream>>>(qbb, kbb, vbT, attn, ctxb);

    // output projection (bf16 MFMA, f32 out)
    gemm_mfma<0><<<ggrid, 256, 0, stream>>>(ctxb, WoT, bo, out, 1024, 1.0f);
}